// Round 1
// baseline (863.156 us; speedup 1.0000x reference)
//
#include <hip/hip_runtime.h>

// FIR band-pass, zero-phase, reflect_limited edges.
// out[t] = sum_{j=0}^{412} h[j] * xs(t + 206 - j)
// xs(s) = x[s]                    , 0 <= s < T
//       = 2*x[0]   - x[-s]        , s < 0        (|s| <= 206 used)
//       = 2*x[T-1] - x[2T-2-s]    , s >= T       (s - (T-1) <= 206 used)

#define T_LEN   30000
#define NTAPS   413
#define HALF    206            // (NTAPS-1)/2
#define BLOCK   256
#define RPT     16             // outputs per thread (consecutive)
#define TILE    (BLOCK * RPT)  // 4096 outputs per block
#define XTILE   (TILE + 2 * HALF)   // 4508 staged samples
#define TILES_PER_SIG 8        // ceil(30000/4096)
#define LDS_PHYS 4800          // padded size: pidx(4511) = 4792

// LDS bank-conflict padding: +1 float per 16 -> lane stride 17 (odd, conflict-free)
__device__ __forceinline__ int pidx(int i) { return i + (i >> 4); }

__global__ __launch_bounds__(BLOCK) void fir_conv_kernel(
    const float* __restrict__ x, const float* __restrict__ h,
    float* __restrict__ out)
{
    __shared__ float lds[LDS_PHYS];
    const int tid  = threadIdx.x;
    const int sig  = blockIdx.x >> 3;     // / TILES_PER_SIG
    const int tile = blockIdx.x & 7;
    const int t0   = tile * TILE;
    const float* xp = x   + (size_t)sig * T_LEN;
    float*       op = out + (size_t)sig * T_LEN;

    // Guard cells (storage s = 0..3): read only by hj==0 tail taps of tid 0.
    // Must be finite so 0*val doesn't make NaN. phys==logical for s<16.
    if (tid < 4) lds[tid] = 0.0f;

    // Stage xtile: storage logical s = l + 4, l in [0, XTILE),
    // xtile[l] = xs(t0 - HALF + l)
    for (int l = tid; l < XTILE; l += BLOCK) {
        int idx = t0 - HALF + l;
        float v;
        if (idx < 0)            v = 2.0f * xp[0]         - xp[-idx];
        else if (idx >= T_LEN)  v = 2.0f * xp[T_LEN - 1] - xp[2 * T_LEN - 2 - idx];
        else                    v = xp[idx];
        lds[pidx(l + 4)] = v;
    }
    __syncthreads();

    float acc[RPT];
    #pragma unroll
    for (int r = 0; r < RPT; ++r) acc[r] = 0.0f;

    // Window invariant at tap j: w[(r + 28 - j) & 15] holds storage
    // s = 16*tid + 4 + (412 - j) + r  (i.e. xs(t + 206 - j) for output r).
    float w[16];
    // phys of storage s = 16*tid + 416 (s ≡ 0 mod 16, so s..s+15 share (s>>4))
    const int q0 = 17 * tid + 442;
    #pragma unroll
    for (int r = 0; r < 16; ++r) w[(r + 12) & 15] = lds[q0 + r];

    // phys of storage s = 16*tid + 415 (s ≡ 15 mod 16: s, s-1, .., s-15 share (s>>4))
    int p0 = q0 - 2;
    for (int jj = 0; jj < 26; ++jj) {       // 26*16 = 416 taps, tail hj = 0
        #pragma unroll
        for (int u = 0; u < 16; ++u) {
            const int j = jj * 16 + u;
            const float hj = (j < NTAPS) ? h[j] : 0.0f;   // wave-uniform -> s_load
            #pragma unroll
            for (int r = 0; r < RPT; ++r)
                acc[r] += hj * w[(r + 28 - u) & 15];
            // preload element for tap j+1 (output r=0): storage s = base + 411 - j
            w[(27 - u) & 15] = lds[p0 - u];
        }
        p0 -= 17;   // 16 logical steps = 17 physical (one pad crossed)
    }

    // Store 16 consecutive outputs as 4x float4 (16B/lane, coalesced).
    const int tbase = t0 + tid * RPT;
    #pragma unroll
    for (int q = 0; q < RPT / 4; ++q) {
        int t = tbase + 4 * q;
        if (t < T_LEN)   // t % 4 == 0 and T_LEN % 4 == 0 -> whole float4 valid
            *reinterpret_cast<float4*>(op + t) =
                make_float4(acc[4*q], acc[4*q+1], acc[4*q+2], acc[4*q+3]);
    }
}

extern "C" void kernel_launch(void* const* d_in, const int* in_sizes, int n_in,
                              void* d_out, int out_size, void* d_ws, size_t ws_size,
                              hipStream_t stream) {
    const float* x = (const float*)d_in[0];
    const float* h = (const float*)d_in[1];
    float* out = (float*)d_out;
    const int nsig = in_sizes[0] / T_LEN;   // 32*64 = 2048
    fir_conv_kernel<<<dim3(nsig * TILES_PER_SIG), dim3(BLOCK), 0, stream>>>(x, h, out);
}

// Round 2
// 437.563 us; speedup vs baseline: 1.9726x; 1.9726x over previous
//
#include <hip/hip_runtime.h>

// Zero-phase FIR band-pass via bf16 MFMA (banded-Toeplitz formulation).
//
// out[t] = sum_{j=0}^{412} h[j] * xs(t + 206 - j)
// xs(s) = x[s] in range; 2*x[0]-x[-s] left; 2*x[T-1]-x[2T-2-s] right.
//
// MFMA mapping (16x16x32 bf16, D[r][n], t = tb + 16n + r):
//   A_sig[r][k] = h[430 + r - k - 32*sig]   (0 if index outside [0,412]),  sig in [0,14)
//   B_sig[k][n] = xs(tb - 224 + 32*sig + k + 16n)
//   out = sum_sig A_sig * B_sig    (each tap j hits exactly one sig)

#define T_LEN   30000
#define NTAPS   413
#define BLOCK   256            // 4 waves
#define OUT_BLK 2048           // outputs per block (8 tiles of 256; 2 tiles/wave)
#define BLK_PER_SIG 15         // ceil(30000/2048)
#define NSIG_A  14             // sigma count (448 effective taps >= 413+15)
#define XS_LEN  2480           // staged samples: OUT_BLK - 256 + 688
#define NCHUNK  310            // XS_LEN / 8 (16B bf16 chunks)
#define LDS_CHUNKS 348         // NCHUNK + NCHUNK/8 padding (16B pad per 128B)

typedef __bf16 bf16x8 __attribute__((ext_vector_type(8)));
typedef float  f32x4  __attribute__((ext_vector_type(4)));

union Chunk {
    uint4 v;
    unsigned short us[8];
    bf16x8 f;
};

__device__ __forceinline__ unsigned short f32_to_bf16_rne(float f) {
    unsigned u = __float_as_uint(f);
    unsigned r = u + 0x7FFFu + ((u >> 16) & 1u);
    return (unsigned short)(r >> 16);
}

// phys index of logical 16B chunk u (pad 1 chunk per 8 -> breaks even-stride conflicts)
__device__ __forceinline__ int cpad(int u) { return u + (u >> 3); }

__global__ void prep_A_kernel(const float* __restrict__ h, uint4* __restrict__ wsA) {
    int i = blockIdx.x * blockDim.x + threadIdx.x;   // 0 .. 14*64-1
    if (i >= NSIG_A * 64) return;
    int sig = i >> 6, lane = i & 63;
    int r = lane & 15, q = lane >> 4;
    Chunk c;
    #pragma unroll
    for (int j = 0; j < 8; ++j) {
        int idx = 430 + r - 8 * q - j - 32 * sig;
        float v = (idx >= 0 && idx < NTAPS) ? h[idx] : 0.0f;
        c.us[j] = f32_to_bf16_rne(v);
    }
    wsA[i] = c.v;
}

__global__ __launch_bounds__(BLOCK, 4) void fir_mfma_kernel(
    const float* __restrict__ x, const uint4* __restrict__ wsA,
    float* __restrict__ out)
{
    __shared__ uint4 lds[LDS_CHUNKS];

    const int tid = threadIdx.x;
    const int sig_id = blockIdx.x / BLK_PER_SIG;
    const int blk    = blockIdx.x % BLK_PER_SIG;
    const int t0 = blk * OUT_BLK;
    const float* xp = x   + (size_t)sig_id * T_LEN;
    float*       op = out + (size_t)sig_id * T_LEN;

    // ---- load A fragments (14 x 16B per lane, hot in L2 after first blocks) ----
    const int lane = tid & 63;
    const int wv   = tid >> 6;
    bf16x8 A[NSIG_A];
    #pragma unroll
    for (int s = 0; s < NSIG_A; ++s) {
        Chunk c; c.v = wsA[s * 64 + lane];
        A[s] = c.f;
    }

    // ---- stage xs (bf16) into LDS: chunk u = elements 8u..8u+7 of
    //      xs(t0 - 224 + l), l in [0, 2480) ----
    for (int u = tid; u < NCHUNK; u += BLOCK) {
        int g0 = t0 - 224 + 8 * u;
        Chunk c;
        if (g0 >= 0 && g0 + 8 <= T_LEN) {
            float4 a = *reinterpret_cast<const float4*>(xp + g0);
            float4 b = *reinterpret_cast<const float4*>(xp + g0 + 4);
            c.us[0] = f32_to_bf16_rne(a.x); c.us[1] = f32_to_bf16_rne(a.y);
            c.us[2] = f32_to_bf16_rne(a.z); c.us[3] = f32_to_bf16_rne(a.w);
            c.us[4] = f32_to_bf16_rne(b.x); c.us[5] = f32_to_bf16_rne(b.y);
            c.us[6] = f32_to_bf16_rne(b.z); c.us[7] = f32_to_bf16_rne(b.w);
        } else {
            float x0 = xp[0], xl = xp[T_LEN - 1];
            #pragma unroll
            for (int j = 0; j < 8; ++j) {
                int g = g0 + j;
                float v;
                if (g < 0)            v = 2.0f * x0 - xp[-g];
                else if (g >= T_LEN)  v = 2.0f * xl - xp[2 * T_LEN - 2 - g];
                else                  v = xp[g];
                c.us[j] = f32_to_bf16_rne(v);
            }
        }
        lds[cpad(u)] = c.v;
    }
    __syncthreads();

    // ---- compute: wave wv owns output tiles mt = 2*wv, 2*wv+1 (256 outputs each).
    // B fragment for (mt, sigma) = chunk u = 32*mt + 4*sigma + 2n + q; tiles share
    // fragments along phi = sigma + 8*(mt - 2*wv). ----
    const int n = lane & 15, q = lane >> 4;
    const int base_u = 64 * wv + 2 * n + q;

    f32x4 acc0 = {0.f, 0.f, 0.f, 0.f};
    f32x4 acc1 = {0.f, 0.f, 0.f, 0.f};

    #pragma unroll
    for (int phi = 0; phi < NSIG_A + 8; ++phi) {   // 22
        int u = base_u + 4 * phi;
        Chunk c; c.v = lds[cpad(u)];
        bf16x8 B = c.f;
        if (phi < NSIG_A)
            acc0 = __builtin_amdgcn_mfma_f32_16x16x32_bf16(A[phi], B, acc0, 0, 0, 0);
        if (phi >= 8)
            acc1 = __builtin_amdgcn_mfma_f32_16x16x32_bf16(A[phi - 8], B, acc1, 0, 0, 0);
    }

    // ---- store: C/D layout col=lane&15 (n), row=(lane>>4)*4+v (r).
    // t = t0 + 256*mt + 16n + 4q + v  -> one float4 per lane, fully coalesced. ----
    const int tA = t0 + 256 * (2 * wv) + 16 * n + 4 * q;
    if (tA < T_LEN)
        *reinterpret_cast<float4*>(op + tA) = make_float4(acc0.x, acc0.y, acc0.z, acc0.w);
    const int tB = tA + 256;
    if (tB < T_LEN)
        *reinterpret_cast<float4*>(op + tB) = make_float4(acc1.x, acc1.y, acc1.z, acc1.w);
}

extern "C" void kernel_launch(void* const* d_in, const int* in_sizes, int n_in,
                              void* d_out, int out_size, void* d_ws, size_t ws_size,
                              hipStream_t stream) {
    const float* x = (const float*)d_in[0];
    const float* h = (const float*)d_in[1];
    float* out = (float*)d_out;
    uint4* wsA = (uint4*)d_ws;                       // 14*64*16 = 14336 B
    const int nsig = in_sizes[0] / T_LEN;            // 2048

    prep_A_kernel<<<dim3(4), dim3(BLOCK), 0, stream>>>(h, wsA);
    fir_mfma_kernel<<<dim3(nsig * BLK_PER_SIG), dim3(BLOCK), 0, stream>>>(x, wsA, out);
}